// Round 8
// baseline (181.183 us; speedup 1.0000x reference)
//
#include <hip/hip_runtime.h>
#include <hip/hip_bf16.h>
#include <stdint.h>

#define D_MODEL 512
#define NH 8
#define DH 64
#define SEQ 4096
#define NBH 16                    // B * NH
#define NX  (2 * SEQ * D_MODEL)   // x element count = 4194304
#define NW  (D_MODEL * D_MODEL)   // one weight matrix = 262144

typedef __attribute__((ext_vector_type(8))) short bf16x8;   // 8 bf16 = 4 VGPRs
typedef __attribute__((ext_vector_type(4))) float f32x4;
typedef __attribute__((ext_vector_type(16))) float f32x16;

// softmax scale folded into W_q at prepass: (1/sqrt(DH)) * log2(e)
#define CSCALE 0.18033688011112042f

// pack two f32 -> bf16x2 in one u32: single v_cvt_pk_bf16_f32 (RNE)
__device__ __forceinline__ uint32_t pkbf(float a, float b) {
    uint32_t r;
    asm("v_cvt_pk_bf16_f32 %0, %1, %2" : "=v"(r) : "v"(a), "v"(b));
    return r;
}

#define SWZ(R) (((R) + ((R) >> 2)) & 3)

// raw barrier: LDS visibility only, does NOT drain in-flight global loads
#define BAR() do {                                          \
    asm volatile("s_waitcnt lgkmcnt(0)" ::: "memory");      \
    __builtin_amdgcn_s_barrier();                           \
} while (0)

// full-drain barrier for global_load_lds staging (LDS dest written by VMEM)
#define BARV() do {                                              \
    asm volatile("s_waitcnt vmcnt(0) lgkmcnt(0)" ::: "memory");  \
    __builtin_amdgcn_s_barrier();                                \
} while (0)

// async global -> LDS, 16 B per lane.  LDS dest wave-uniform; lane i lands
// at ldsbase + i*16.  Global addr per-lane.
typedef const __attribute__((address_space(1))) void* gvp;
typedef __attribute__((address_space(3))) void* lvp;
__device__ __forceinline__ void gload16(const short* g, short* l) {
    __builtin_amdgcn_global_load_lds((gvp)g, (lvp)l, 16, 0, 0);
}

// convert 8 fp32 (2 float4) -> bf16x8 with scale
__device__ __forceinline__ bf16x8 cvt8(float4 u, float4 v, float s) {
    union { uint32_t w[4]; bf16x8 h; } r;
    r.w[0] = pkbf(u.x * s, u.y * s); r.w[1] = pkbf(u.z * s, u.w * s);
    r.w[2] = pkbf(v.x * s, v.y * s); r.w[3] = pkbf(v.z * s, v.w * s);
    return r.h;
}

// ---------------------------------------------------------------------------
// Kernel 0: bf16 prepass.  x -> xb (in d_out, dead until proj), W* -> Wb,
// CSCALE folded into Wq.  ~30 MB, BW-bound.
// ---------------------------------------------------------------------------
__global__ __launch_bounds__(256) void cvt_pre(
    const float* __restrict__ x,
    const float* __restrict__ Wq, const float* __restrict__ Wk,
    const float* __restrict__ Wv, const float* __restrict__ Wp,
    short* __restrict__ xb, short* __restrict__ Wb)
{
    const size_t t = ((size_t)blockIdx.x * 256 + threadIdx.x) * 8;
    const float* src; short* dst; float s = 1.0f; size_t off;
    if (t < NX) {
        src = x; dst = xb; off = t;
    } else {
        const size_t u = t - NX;
        const int w = (int)(u >> 18);            // NW = 2^18
        off = u & (NW - 1);
        src = (w == 0) ? Wq : (w == 1) ? Wk : (w == 2) ? Wv : Wp;
        dst = Wb + ((size_t)w << 18);
        s = (w == 0) ? CSCALE : 1.0f;
    }
    float4 a = *(const float4*)(src + off);
    float4 b = *(const float4*)(src + off + 4);
    *(bf16x8*)(dst + off) = cvt8(a, b, s);
}

// ---------------------------------------------------------------------------
// Kernel 1: fused QKV projection, all-bf16, global_load_lds staging.
// Q/K epilogue: in-wave LDS transpose (swizzled) then 8 coalesced dwordx4
// stores per thread (replaces 64 scalar 2B stores/thread).
// ---------------------------------------------------------------------------
__global__ __launch_bounds__(256) void qkv_kernel(
    const short* __restrict__ xb, const short* __restrict__ Wb,
    short* __restrict__ Qb, short* __restrict__ Kb, short* __restrict__ Vt)
{
    __shared__ __align__(16) short at[2][4096];   // 128 x 32 bf16
    __shared__ __align__(16) short bt[2][4096];

    const int tid  = threadIdx.x;
    const int wave = tid >> 6;
    const int lane = tid & 63;
    const int ln = lane & 15, quad = lane >> 4;
    const int z = blockIdx.z;
    const short* W = Wb + ((size_t)z << 18);
    const int m0 = blockIdx.x * 128;
    const int n0 = blockIdx.y * 128;
    const int mh = (wave & 1) * 64, nh = (wave >> 1) * 64;

    // staging: chunk ck holds global (row R=ck>>2, col-chunk (ck&3)^SWZ(R)).
    // gload_lds writes lane-linear, so the swizzle lives in the SOURCE addr.
    const int ck0 = tid, ck1 = tid + 256;
    const int R0 = ck0 >> 2, R1 = ck1 >> 2;
    const int c0 = (ck0 & 3) ^ SWZ(R0), c1 = (ck1 & 3) ^ SWZ(R1);
    const int lbase = (tid & 192) * 8;            // wave-uniform chunk base

    auto stage = [&](int buf, int kc) {
        const short* gA0 = xb + (size_t)(m0 + R0) * D_MODEL + kc + c0 * 8;
        const short* gA1 = xb + (size_t)(m0 + R1) * D_MODEL + kc + c1 * 8;
        const short* gB0 = W + (size_t)(n0 + R0) * D_MODEL + kc + c0 * 8;
        const short* gB1 = W + (size_t)(n0 + R1) * D_MODEL + kc + c1 * 8;
        gload16(gA0, &at[buf][lbase]);
        gload16(gA1, &at[buf][lbase] + 2048);
        gload16(gB0, &bt[buf][lbase]);
        gload16(gB1, &bt[buf][lbase] + 2048);
    };

    f32x4 acc[4][4] = {};

    stage(0, 0);

    for (int s = 0; s < 16; ++s) {
        const int cur = s & 1;
        BARV();                                   // buf[cur] landed, reads done
        if (s < 15) stage(cur ^ 1, (s + 1) * 32);

        bf16x8 a[4], b[4];
#pragma unroll
        for (int i = 0; i < 4; ++i) {
            const int R = mh + i * 16 + ln;
            a[i] = *(const bf16x8*)(&at[cur][R * 32 + ((quad ^ SWZ(R)) * 8)]);
        }
#pragma unroll
        for (int j = 0; j < 4; ++j) {
            const int R = nh + j * 16 + ln;
            b[j] = *(const bf16x8*)(&bt[cur][R * 32 + ((quad ^ SWZ(R)) * 8)]);
        }
        __builtin_amdgcn_s_setprio(1);
#pragma unroll
        for (int i = 0; i < 4; ++i)
#pragma unroll
            for (int j = 0; j < 4; ++j)
                acc[i][j] = __builtin_amdgcn_mfma_f32_16x16x32_bf16(
                    a[i], b[j], acc[i][j], 0, 0, 0);
        __builtin_amdgcn_s_setprio(0);
    }

    if (z == 2) {
#pragma unroll
        for (int i = 0; i < 4; ++i) {
            const int row0 = m0 + mh + i * 16 + quad * 4;
            const int bb = row0 >> 12, sq = row0 & (SEQ - 1);
#pragma unroll
            for (int j = 0; j < 4; ++j) {
                const int n = n0 + nh + j * 16 + ln;
                const int h = n >> 6, dh = n & 63;
                uint2 st;
                st.x = pkbf(acc[i][j][0], acc[i][j][1]);
                st.y = pkbf(acc[i][j][2], acc[i][j][3]);
                *(uint2*)(Vt + (size_t)((bb * NH + h) * DH + dh) * SEQ + sq) = st;
            }
        }
    } else {
        short* P = (z == 0) ? Qb : Kb;
        BAR();                                    // all waves done with LDS
        // per-wave 64x64 scratch (8 KB): wave0->at[0] w1->at[1] w2->bt[0] w3->bt[1]
        short* scratch = (wave < 2) ? &at[wave][0] : &bt[wave - 2][0];
        // write: value (row lr, col lc) at [lr][ (lc>>3 ^ (lr&7))*8 + (lc&7) ]
#pragma unroll
        for (int i = 0; i < 4; ++i)
#pragma unroll
            for (int j = 0; j < 4; ++j) {
                const uint32_t lo  = pkbf(acc[i][j][0], acc[i][j][1]);
                const uint32_t hi2 = pkbf(acc[i][j][2], acc[i][j][3]);
                const int lc = 16 * j + ln;
                const int cw = lc & 7, ch = lc >> 3;
#pragma unroll
                for (int r = 0; r < 4; ++r) {
                    const int lr = 16 * i + 4 * quad + r;
                    const uint32_t w = (r < 2) ? lo : hi2;
                    scratch[lr * 64 + ((ch ^ (lr & 7)) << 3) + cw] =
                        (short)((r & 1) ? (w >> 16) : (w & 0xffff));
                }
            }
        asm volatile("s_waitcnt lgkmcnt(0)" ::: "memory");
        // read back: lane = row, 8 chunks of 8 dh -> coalesced dwordx4 stores
        const int hh = (n0 + nh) >> 6;
        const int rg = m0 + mh + lane;
        const int bb2 = rg >> 12, sq2 = rg & (SEQ - 1);
        short* dst = P + (((size_t)(bb2 * NH + hh) * SEQ + sq2) << 6);
#pragma unroll
        for (int c = 0; c < 8; ++c) {
            const int swc = c ^ (lane & 7);
            *(bf16x8*)(dst + 8 * c) =
                *(const bf16x8*)&scratch[lane * 64 + swc * 8];
        }
    }
}

// ---------------------------------------------------------------------------
// Kernel 2: causal flash attention, S^T, 32x32x16, NO-MAX softmax.
// DEFERRED-PV software pipeline (T15): tile j's P-fragments and V-rows kept
// in registers; PV(j-1)+l(j-1) execute right after QK(j)'s MFMAs are issued
// (20 back-to-back MFMAs cover QK latency); softmax VALU phase of tile j
// overlaps the MFMA pipe drain.
// ---------------------------------------------------------------------------
__global__ __launch_bounds__(256) void attn_kernel(
    const short* __restrict__ Qb, const short* __restrict__ Kb,
    const short* __restrict__ Vt, short* __restrict__ ao)
{
    __shared__ __align__(16) short kt[2][4096];   // 64 keys x 64 dh (kappa rows)
    __shared__ __align__(16) short vt[2][4096];   // 64 dh x 64 keys

    const int tid  = threadIdx.x;                 // 0..255
    const int wave = tid >> 6;
    const int lane = tid & 63;
    const int l31 = lane & 31, hi = lane >> 5;
    const int bh = blockIdx.y;
    const int w_ = (blockIdx.x + 4 * bh) & 31;
    const int g2 = ((bh >> 3) & 1) ? (31 - w_) : w_;   // 0..31
    const short* Qp = Qb + (size_t)bh * SEQ * DH;
    const short* Kp = Kb + (size_t)bh * SEQ * DH;
    const short* Vp = Vt + (size_t)bh * DH * SEQ;
    const int bb = bh >> 3, h = bh & 7;
    const int q0 = g2 * 128 + wave * 32;          // this wave's 32 q-rows
    const int myq = q0 + l31;
    const int jdiag = q0 >> 6;                    // wave's diagonal tile
    const int jmax = 2 * g2 + 1;

    // ---- per-thread staging constants (2 chunks per array) ----
    const int ckA = tid, ckB = tid + 256;
    const int RA = ckA >> 3, RB = ckB >> 3;
    const int cA = (ckA & 7) ^ (RA & 7), cB = (ckB & 7) ^ (RB & 7);
    const int RA31 = RA & 31, RB31 = RB & 31;
    const int kkA = (RA & 32) + ((RA31 & 8) << 1) + ((RA31 & 4) << 1)
                  + ((RA31 & 16) >> 2) + (RA31 & 3);
    const int kkB = (RB & 32) + ((RB31 & 8) << 1) + ((RB31 & 4) << 1)
                  + ((RB31 & 16) >> 2) + (RB31 & 3);
    const size_t kOffA = ((size_t)kkA << 6) + cA * 8;
    const size_t kOffB = ((size_t)kkB << 6) + cB * 8;
    const size_t vOffA = (size_t)RA * SEQ + cA * 8;
    const size_t vOffB = (size_t)RB * SEQ + cB * 8;

    bf16x8 sk0, sk1, sv0, sv1;                    // staged regs
    auto load_tile = [&](int j) {
        const size_t k0 = (size_t)j * 64;
        sk0 = *(const bf16x8*)(Kp + (k0 << 6) + kOffA);
        sk1 = *(const bf16x8*)(Kp + (k0 << 6) + kOffB);
        sv0 = *(const bf16x8*)(Vp + vOffA + k0);
        sv1 = *(const bf16x8*)(Vp + vOffB + k0);
    };
    auto write_tile = [&](int buf) {
        *(bf16x8*)&kt[buf][ckA * 8] = sk0;
        *(bf16x8*)&kt[buf][ckB * 8] = sk1;
        *(bf16x8*)&vt[buf][ckA * 8] = sv0;
        *(bf16x8*)&vt[buf][ckB * 8] = sv1;
    };

    // Q B-frags: qf[c] = Q[myq][16c + 8hi .. +7]
    bf16x8 qf[4];
#pragma unroll
    for (int c = 0; c < 4; ++c)
        qf[c] = *(const bf16x8*)(Qp + (size_t)myq * DH + c * 16 + hi * 8);

    // all-ones bf16 A-fragment for the l-reduction MFMA
    const bf16x8 ones = { (short)0x3F80, (short)0x3F80, (short)0x3F80,
                          (short)0x3F80, (short)0x3F80, (short)0x3F80,
                          (short)0x3F80, (short)0x3F80 };

    f32x16 o0 = {}, o1 = {};
    f32x16 lacc = {};                             // every reg = sum_k P[k][q=l31]

    // deferred-PV state (registers; static indexing only)
    bf16x8 vp0, vp1, vp2, vp3, vp4, vp5, vp6, vp7;
    bf16x8 pp0, pp1, pp2, pp3;
    bool havePrev = false;

    load_tile(0);
    write_tile(0);
    load_tile(1);
    BAR();

    for (int j = 0; j <= jmax; ++j) {
        const int cur = j & 1;
        if (j < jmax) {
            write_tile(cur ^ 1);                  // regs from 1 iter ago
            if (j + 1 < jmax) load_tile(j + 2);   // in flight over 2 iters
        }

        const bool comp = ((j << 6) <= q0 + 31);  // wave-uniform
        f32x16 s0 = {}, s1 = {};
        const int sw = l31 & 7;

        __builtin_amdgcn_s_setprio(1);
        if (comp) {
            // ---- S^T = K.Q^T, two 32-key subtiles ----
#pragma unroll
            for (int c = 0; c < 4; ++c) {
                const int pc = ((2 * c + hi) ^ sw) * 8;
                bf16x8 a0 = *(const bf16x8*)(&kt[cur][l31 * 64 + pc]);
                bf16x8 a1 = *(const bf16x8*)(&kt[cur][(32 + l31) * 64 + pc]);
                s0 = __builtin_amdgcn_mfma_f32_32x32x16_bf16(a0, qf[c], s0, 0, 0, 0);
                s1 = __builtin_amdgcn_mfma_f32_32x32x16_bf16(a1, qf[c], s1, 0, 0, 0);
            }
        }
        if (havePrev) {
            // ---- deferred PV(j-1) + l(j-1): pure-register MFMAs that
            //      cover QK(j)'s pipe latency ----
            lacc = __builtin_amdgcn_mfma_f32_32x32x16_bf16(ones, pp0, lacc, 0, 0, 0);
            lacc = __builtin_amdgcn_mfma_f32_32x32x16_bf16(ones, pp1, lacc, 0, 0, 0);
            lacc = __builtin_amdgcn_mfma_f32_32x32x16_bf16(ones, pp2, lacc, 0, 0, 0);
            lacc = __builtin_amdgcn_mfma_f32_32x32x16_bf16(ones, pp3, lacc, 0, 0, 0);
            o0 = __builtin_amdgcn_mfma_f32_32x32x16_bf16(vp0, pp0, o0, 0, 0, 0);
            o0 = __builtin_amdgcn_mfma_f32_32x32x16_bf16(vp1, pp1, o0, 0, 0, 0);
            o0 = __builtin_amdgcn_mfma_f32_32x32x16_bf16(vp2, pp2, o0, 0, 0, 0);
            o0 = __builtin_amdgcn_mfma_f32_32x32x16_bf16(vp3, pp3, o0, 0, 0, 0);
            o1 = __builtin_amdgcn_mfma_f32_32x32x16_bf16(vp4, pp0, o1, 0, 0, 0);
            o1 = __builtin_amdgcn_mfma_f32_32x32x16_bf16(vp5, pp1, o1, 0, 0, 0);
            o1 = __builtin_amdgcn_mfma_f32_32x32x16_bf16(vp6, pp2, o1, 0, 0, 0);
            o1 = __builtin_amdgcn_mfma_f32_32x32x16_bf16(vp7, pp3, o1, 0, 0, 0);
        }
        __builtin_amdgcn_s_setprio(0);

        if (comp) {
            // ---- V(j) -> regs (consumed next iter; LDS buf gets
            //      overwritten at iter j+1, regs are safe) ----
            {
                const short* vrow = &vt[cur][l31 * 64];
                vp0 = *(const bf16x8*)(vrow + (((0 + hi) ^ sw) * 8));
                vp1 = *(const bf16x8*)(vrow + (((2 + hi) ^ sw) * 8));
                vp2 = *(const bf16x8*)(vrow + (((4 + hi) ^ sw) * 8));
                vp3 = *(const bf16x8*)(vrow + (((6 + hi) ^ sw) * 8));
            }
            {
                const short* vrow = &vt[cur][(32 + l31) * 64];
                vp4 = *(const bf16x8*)(vrow + (((0 + hi) ^ sw) * 8));
                vp5 = *(const bf16x8*)(vrow + (((2 + hi) ^ sw) * 8));
                vp6 = *(const bf16x8*)(vrow + (((4 + hi) ^ sw) * 8));
                vp7 = *(const bf16x8*)(vrow + (((6 + hi) ^ sw) * 8));
            }
            // ---- causal mask at/after this wave's diagonal ----
            if (j >= jdiag) {
                const int k0 = j * 64;
#pragma unroll
                for (int reg = 0; reg < 16; ++reg) {
                    const int kl = ((reg >> 2) & 1) * 16 + hi * 8
                                 + ((reg >> 3) & 1) * 4 + (reg & 3);
                    if (k0 + kl > myq)      s0[reg] = -3e38f;
                    if (k0 + 32 + kl > myq) s1[reg] = -3e38f;
                }
            }
            // ---- NO-MAX softmax: p = exp2(s) (overlaps MFMA pipe drain) ----
#pragma unroll
            for (int i = 0; i < 16; ++i) {
                s0[i] = __builtin_amdgcn_exp2f(s0[i]);
                s1[i] = __builtin_amdgcn_exp2f(s1[i]);
            }
            // ---- P B-frags straight from C regs (kappa permutation) ----
            union { uint32_t u[4]; bf16x8 v; } P00, P01, P10, P11;
            P00.u[0] = pkbf(s0[0], s0[1]);   P00.u[1] = pkbf(s0[2], s0[3]);
            P00.u[2] = pkbf(s0[8], s0[9]);   P00.u[3] = pkbf(s0[10], s0[11]);
            P01.u[0] = pkbf(s0[4], s0[5]);   P01.u[1] = pkbf(s0[6], s0[7]);
            P01.u[2] = pkbf(s0[12], s0[13]); P01.u[3] = pkbf(s0[14], s0[15]);
            P10.u[0] = pkbf(s1[0], s1[1]);   P10.u[1] = pkbf(s1[2], s1[3]);
            P10.u[2] = pkbf(s1[8], s1[9]);   P10.u[3] = pkbf(s1[10], s1[11]);
            P11.u[0] = pkbf(s1[4], s1[5]);   P11.u[1] = pkbf(s1[6], s1[7]);
            P11.u[2] = pkbf(s1[12], s1[13]); P11.u[3] = pkbf(s1[14], s1[15]);
            pp0 = P00.v; pp1 = P01.v; pp2 = P10.v; pp3 = P11.v;
        }
        havePrev = comp;
        BAR();
    }
    // ---- flush deferred PV of the last computed tile ----
    if (havePrev) {
        __builtin_amdgcn_s_setprio(1);
        lacc = __builtin_amdgcn_mfma_f32_32x32x16_bf16(ones, pp0, lacc, 0, 0, 0);
        lacc = __builtin_amdgcn_mfma_f32_32x32x16_bf16(ones, pp1, lacc, 0, 0, 0);
        lacc = __builtin_amdgcn_mfma_f32_32x32x16_bf16(ones, pp2, lacc, 0, 0, 0);
        lacc = __builtin_amdgcn_mfma_f32_32x32x16_bf16(ones, pp3, lacc, 0, 0, 0);
        o0 = __builtin_amdgcn_mfma_f32_32x32x16_bf16(vp0, pp0, o0, 0, 0, 0);
        o0 = __builtin_amdgcn_mfma_f32_32x32x16_bf16(vp1, pp1, o0, 0, 0, 0);
        o0 = __builtin_amdgcn_mfma_f32_32x32x16_bf16(vp2, pp2, o0, 0, 0, 0);
        o0 = __builtin_amdgcn_mfma_f32_32x32x16_bf16(vp3, pp3, o0, 0, 0, 0);
        o1 = __builtin_amdgcn_mfma_f32_32x32x16_bf16(vp4, pp0, o1, 0, 0, 0);
        o1 = __builtin_amdgcn_mfma_f32_32x32x16_bf16(vp5, pp1, o1, 0, 0, 0);
        o1 = __builtin_amdgcn_mfma_f32_32x32x16_bf16(vp6, pp2, o1, 0, 0, 0);
        o1 = __builtin_amdgcn_mfma_f32_32x32x16_bf16(vp7, pp3, o1, 0, 0, 0);
        __builtin_amdgcn_s_setprio(0);
    }
    // ---- normalize by lacc[0] (full sum; identical in both half-waves) ----
    const float inv = 1.0f / lacc[0];
    short* orow = ao + (size_t)(bb * SEQ + myq) * D_MODEL + h * DH;
#pragma unroll
    for (int c = 0; c < 4; ++c) {
        uint2 st;
        st.x = pkbf(o0[4 * c] * inv,     o0[4 * c + 1] * inv);
        st.y = pkbf(o0[4 * c + 2] * inv, o0[4 * c + 3] * inv);
        *(uint2*)(orow + 8 * c + 4 * hi) = st;
    }
#pragma unroll
    for (int c = 0; c < 4; ++c) {
        uint2 st;
        st.x = pkbf(o1[4 * c] * inv,     o1[4 * c + 1] * inv);
        st.y = pkbf(o1[4 * c + 2] * inv, o1[4 * c + 3] * inv);
        *(uint2*)(orow + 32 + 8 * c + 4 * hi) = st;
    }
}

// ---------------------------------------------------------------------------
// Kernel 3: output projection, all-bf16, global_load_lds staging.
// 64m x 128n tiles (512 blocks, 2/CU).
// ---------------------------------------------------------------------------
__global__ __launch_bounds__(256) void proj_kernel(
    const short* __restrict__ attn, const short* __restrict__ Wpb,
    const float* __restrict__ bias, float* __restrict__ out)
{
    __shared__ __align__(16) short at[2][2048];   // 64 x 32
    __shared__ __align__(16) short bt[2][4096];   // 128 x 32

    const int tid  = threadIdx.x;
    const int wave = tid >> 6;
    const int lane = tid & 63;
    const int ln = lane & 15, quad = lane >> 4;
    const int m0 = blockIdx.x * 64;
    const int n0 = blockIdx.y * 128;
    const int mh = (wave & 1) * 32, nh = (wave >> 1) * 64;

    const int RA = tid >> 2, cAc = (tid & 3) ^ SWZ(RA);
    const int ck0 = tid, ck1 = tid + 256;
    const int R0 = ck0 >> 2, R1 = ck1 >> 2;
    const int c0 = (ck0 & 3) ^ SWZ(R0), c1 = (ck1 & 3) ^ SWZ(R1);
    const int lbase = (tid & 192) * 8;            // wave-uniform chunk base

    auto stage = [&](int buf, int kc) {
        const short* gA = attn + (size_t)(m0 + RA) * D_MODEL + kc + cAc * 8;
        const short* gB0 = Wpb + (size_t)(n0 + R0) * D_MODEL + kc + c0 * 8;
        const short* gB1 = Wpb + (size_t)(n0 + R1) * D_MODEL + kc + c1 * 8;
        gload16(gA, &at[buf][lbase]);
        gload16(gB0, &bt[buf][lbase]);
        gload16(gB1, &bt[buf][lbase] + 2048);
    };

    f32x4 acc[2][4] = {};

    stage(0, 0);

    for (int s = 0; s < 16; ++s) {
        const int cur = s & 1;
        BARV();
        if (s < 15) stage(cur ^ 1, (s + 1) * 32);

        bf16x8 a[2], b[4];
#pragma unroll
        for (int i = 0; i < 2; ++i) {
            const int R = mh + i * 16 + ln;
            a[i] = *(const bf16x8*)(&at[cur][R * 32 + ((quad ^ SWZ(R)) * 8)]);
        }
#pragma unroll
        for (int j = 0; j < 4; ++j) {
            const int R = nh + j * 16 + ln;
            b[j] = *(const bf16x8*)(&bt[cur][R * 32 + ((quad ^ SWZ(R)) * 8)]);
        }
        __builtin_amdgcn_s_setprio(1);
#pragma unroll
        for (int i = 0; i < 2; ++i)
#pragma unroll
            for (int j = 0; j < 4; ++j)
                acc[i][j] = __builtin_amdgcn_mfma_f32_16x16x32_bf16(
                    a[i], b[j], acc[i][j], 0, 0, 0);
        __builtin_amdgcn_s_setprio(0);
    }
#pragma unroll
    for (int j = 0; j < 4; ++j) {
        const int n = n0 + nh + j * 16 + ln;
        const float bv = bias[n];
#pragma unroll
        for (int i = 0; i < 2; ++i)
#pragma unroll
            for (int r = 0; r < 4; ++r) {
                const int row = m0 + mh + i * 16 + quad * 4 + r;
                out[(size_t)row * D_MODEL + n] = acc[i][j][r] + bv;
            }
    }
}

extern "C" void kernel_launch(void* const* d_in, const int* in_sizes, int n_in,
                              void* d_out, int out_size, void* d_ws, size_t ws_size,
                              hipStream_t stream) {
    const float* x  = (const float*)d_in[0];
    const float* Wq = (const float*)d_in[1];
    const float* Wk = (const float*)d_in[2];
    const float* Wv = (const float*)d_in[3];
    const float* Wp = (const float*)d_in[4];
    const float* bp = (const float*)d_in[5];
    float* out = (float*)d_out;

    // workspace: Qb | Kb | Vt | ab (4 x 8 MB bf16) | Wb (4 x 0.5 MB bf16)
    short* Qb = (short*)d_ws;
    short* Kb = Qb + (size_t)NBH * SEQ * DH;
    short* Vt = Kb + (size_t)NBH * SEQ * DH;
    short* ab = Vt + (size_t)NBH * SEQ * DH;
    short* Wb = ab + (size_t)NBH * SEQ * DH;

    // xb (8.4 MB bf16) lives in d_out (16.78 MB), dead until proj overwrites
    short* xb = (short*)d_out;

    cvt_pre<<<dim3((NX + 4 * NW) / (8 * 256)), 256, 0, stream>>>(
        x, Wq, Wk, Wv, Wp, xb, Wb);
    qkv_kernel<<<dim3(64, 4, 3), 256, 0, stream>>>(xb, Wb, Qb, Kb, Vt);
    attn_kernel<<<dim3(32, NBH), 256, 0, stream>>>(Qb, Kb, Vt, ab);
    proj_kernel<<<dim3(128, 4), 256, 0, stream>>>(ab, Wb + 3 * (size_t)NW, bp, out);
}

// Round 9
// 168.213 us; speedup vs baseline: 1.0771x; 1.0771x over previous
//
#include <hip/hip_runtime.h>
#include <hip/hip_bf16.h>
#include <stdint.h>

#define D_MODEL 512
#define NH 8
#define DH 64
#define SEQ 4096
#define NBH 16                    // B * NH
#define NX  (2 * SEQ * D_MODEL)   // x element count = 4194304
#define NW  (D_MODEL * D_MODEL)   // one weight matrix = 262144

typedef __attribute__((ext_vector_type(8))) short bf16x8;   // 8 bf16 = 4 VGPRs
typedef __attribute__((ext_vector_type(4))) float f32x4;
typedef __attribute__((ext_vector_type(16))) float f32x16;

// softmax scale folded into W_q at prepass: (1/sqrt(DH)) * log2(e)
#define CSCALE 0.18033688011112042f

// pack two f32 -> bf16x2 in one u32: single v_cvt_pk_bf16_f32 (RNE)
__device__ __forceinline__ uint32_t pkbf(float a, float b) {
    uint32_t r;
    asm("v_cvt_pk_bf16_f32 %0, %1, %2" : "=v"(r) : "v"(a), "v"(b));
    return r;
}

#define SWZ(R) (((R) + ((R) >> 2)) & 3)

// raw barrier: LDS visibility only, does NOT drain in-flight global loads
#define BAR() do {                                          \
    asm volatile("s_waitcnt lgkmcnt(0)" ::: "memory");      \
    __builtin_amdgcn_s_barrier();                           \
} while (0)

// counted barrier: wait until <=N vmem ops outstanding (oldest stage landed),
// drain LDS ops, then barrier.  Loads of NEWER stages stay in flight.
#define BARC(N) do {                                                     \
    asm volatile("s_waitcnt vmcnt(" #N ") lgkmcnt(0)" ::: "memory");     \
    __builtin_amdgcn_s_barrier();                                        \
} while (0)

// async global -> LDS, 16 B per lane.  LDS dest wave-uniform; lane i lands
// at ldsbase + i*16.  Global addr per-lane.
typedef const __attribute__((address_space(1))) void* gvp;
typedef __attribute__((address_space(3))) void* lvp;
__device__ __forceinline__ void gload16(const short* g, short* l) {
    __builtin_amdgcn_global_load_lds((gvp)g, (lvp)l, 16, 0, 0);
}

// convert 8 fp32 (2 float4) -> bf16x8 with scale
__device__ __forceinline__ bf16x8 cvt8(float4 u, float4 v, float s) {
    union { uint32_t w[4]; bf16x8 h; } r;
    r.w[0] = pkbf(u.x * s, u.y * s); r.w[1] = pkbf(u.z * s, u.w * s);
    r.w[2] = pkbf(v.x * s, v.y * s); r.w[3] = pkbf(v.z * s, v.w * s);
    return r.h;
}

// ---------------------------------------------------------------------------
// Kernel 0: bf16 prepass.  x -> xb (in d_out, dead until proj), W* -> Wb,
// CSCALE folded into Wq.  ~30 MB, BW-bound.
// ---------------------------------------------------------------------------
__global__ __launch_bounds__(256) void cvt_pre(
    const float* __restrict__ x,
    const float* __restrict__ Wq, const float* __restrict__ Wk,
    const float* __restrict__ Wv, const float* __restrict__ Wp,
    short* __restrict__ xb, short* __restrict__ Wb)
{
    const size_t t = ((size_t)blockIdx.x * 256 + threadIdx.x) * 8;
    const float* src; short* dst; float s = 1.0f; size_t off;
    if (t < NX) {
        src = x; dst = xb; off = t;
    } else {
        const size_t u = t - NX;
        const int w = (int)(u >> 18);            // NW = 2^18
        off = u & (NW - 1);
        src = (w == 0) ? Wq : (w == 1) ? Wk : (w == 2) ? Wv : Wp;
        dst = Wb + ((size_t)w << 18);
        s = (w == 0) ? CSCALE : 1.0f;
    }
    float4 a = *(const float4*)(src + off);
    float4 b = *(const float4*)(src + off + 4);
    *(bf16x8*)(dst + off) = cvt8(a, b, s);
}

// ---------------------------------------------------------------------------
// Kernel 1: fused QKV projection, all-bf16, global_load_lds staging with
// 3-buffer rotation + COUNTED vmcnt (T4).  The old per-step vmcnt(0) drain
// exposed the full load latency every K-step (m97/m233 2-phase stall) —
// now only the oldest stage must have landed; the prefetch stays in flight
// across the barrier.  One barrier per step.
// ---------------------------------------------------------------------------
__global__ __launch_bounds__(256) void qkv_kernel(
    const short* __restrict__ xb, const short* __restrict__ Wb,
    short* __restrict__ Qb, short* __restrict__ Kb, short* __restrict__ Vt)
{
    __shared__ __align__(16) short at[3][4096];   // 3 x (128 x 32) bf16
    __shared__ __align__(16) short bt[3][4096];

    const int tid  = threadIdx.x;
    const int wave = tid >> 6;
    const int lane = tid & 63;
    const int ln = lane & 15, quad = lane >> 4;
    const int z = blockIdx.z;
    const short* W = Wb + ((size_t)z << 18);
    const int m0 = blockIdx.x * 128;
    const int n0 = blockIdx.y * 128;
    const int mh = (wave & 1) * 64, nh = (wave >> 1) * 64;

    // staging: chunk ck holds global (row R=ck>>2, col-chunk (ck&3)^SWZ(R)).
    // gload_lds writes lane-linear, so the swizzle lives in the SOURCE addr.
    const int ck0 = tid, ck1 = tid + 256;
    const int R0 = ck0 >> 2, R1 = ck1 >> 2;
    const int c0 = (ck0 & 3) ^ SWZ(R0), c1 = (ck1 & 3) ^ SWZ(R1);
    const int lbase = (tid & 192) * 8;            // wave-uniform chunk base

    auto stage = [&](int buf, int kc) {
        const short* gA0 = xb + (size_t)(m0 + R0) * D_MODEL + kc + c0 * 8;
        const short* gA1 = xb + (size_t)(m0 + R1) * D_MODEL + kc + c1 * 8;
        const short* gB0 = W + (size_t)(n0 + R0) * D_MODEL + kc + c0 * 8;
        const short* gB1 = W + (size_t)(n0 + R1) * D_MODEL + kc + c1 * 8;
        gload16(gA0, &at[buf][lbase]);
        gload16(gA1, &at[buf][lbase] + 2048);
        gload16(gB0, &bt[buf][lbase]);
        gload16(gB1, &bt[buf][lbase] + 2048);
    };

    f32x4 acc[4][4] = {};

    stage(0, 0);
    stage(1, 32);

    for (int s = 0; s < 16; ++s) {
        const int cur = s % 3;
        // steady state: {stage s (4), stage s+1 (4)} outstanding -> wait 4
        // (oldest = stage s, the buffer we're about to read).  Last step:
        // only stage 15 outstanding -> full wait.
        if (s == 15) BARC(0); else BARC(4);
        // issue the prefetch FIRST: buf (s+2)%3 == (s-1)%3, whose readers
        // all finished before the barrier we just passed (lgkmcnt(0)).
        if (s < 14) stage((s + 2) % 3, (s + 2) * 32);

        bf16x8 a[4], b[4];
#pragma unroll
        for (int i = 0; i < 4; ++i) {
            const int R = mh + i * 16 + ln;
            a[i] = *(const bf16x8*)(&at[cur][R * 32 + ((quad ^ SWZ(R)) * 8)]);
        }
#pragma unroll
        for (int j = 0; j < 4; ++j) {
            const int R = nh + j * 16 + ln;
            b[j] = *(const bf16x8*)(&bt[cur][R * 32 + ((quad ^ SWZ(R)) * 8)]);
        }
        __builtin_amdgcn_s_setprio(1);
#pragma unroll
        for (int i = 0; i < 4; ++i)
#pragma unroll
            for (int j = 0; j < 4; ++j)
                acc[i][j] = __builtin_amdgcn_mfma_f32_16x16x32_bf16(
                    a[i], b[j], acc[i][j], 0, 0, 0);
        __builtin_amdgcn_s_setprio(0);
    }

    if (z == 2) {
#pragma unroll
        for (int i = 0; i < 4; ++i) {
            const int row0 = m0 + mh + i * 16 + quad * 4;
            const int bb = row0 >> 12, sq = row0 & (SEQ - 1);
#pragma unroll
            for (int j = 0; j < 4; ++j) {
                const int n = n0 + nh + j * 16 + ln;
                const int h = n >> 6, dh = n & 63;
                uint2 st;
                st.x = pkbf(acc[i][j][0], acc[i][j][1]);
                st.y = pkbf(acc[i][j][2], acc[i][j][3]);
                *(uint2*)(Vt + (size_t)((bb * NH + h) * DH + dh) * SEQ + sq) = st;
            }
        }
    } else {
        short* P = (z == 0) ? Qb : Kb;
#pragma unroll
        for (int i = 0; i < 4; ++i)
#pragma unroll
            for (int j = 0; j < 4; ++j) {
                const int n = n0 + nh + j * 16 + ln;
                const int h = n >> 6, dh = n & 63;
                const uint32_t lo = pkbf(acc[i][j][0], acc[i][j][1]);
                const uint32_t hi2 = pkbf(acc[i][j][2], acc[i][j][3]);
#pragma unroll
                for (int r = 0; r < 4; ++r) {
                    const int row = m0 + mh + i * 16 + quad * 4 + r;
                    const int bb = row >> 12, sq = row & (SEQ - 1);
                    const uint32_t w = (r < 2) ? lo : hi2;
                    P[((size_t)((bb * NH + h) * SEQ + sq) << 6) + dh] =
                        (short)((r & 1) ? (w >> 16) : (w & 0xffff));
                }
            }
    }
}

// ---------------------------------------------------------------------------
// Kernel 2: causal flash attention — EXACT r3/r4/r6 form (69.8-71.7 us,
// 4x measured).  Reg-staged K/V, raw-barrier prefetch survival, setprio,
// wave-uniform masked-tile skip, NO-MAX softmax with MFMA l-reduction.
// (r8's deferred-PV reverted: +10.5 us, T15 null on lockstep structure.)
// ---------------------------------------------------------------------------
__global__ __launch_bounds__(256) void attn_kernel(
    const short* __restrict__ Qb, const short* __restrict__ Kb,
    const short* __restrict__ Vt, short* __restrict__ ao)
{
    __shared__ __align__(16) short kt[2][4096];   // 64 keys x 64 dh (kappa rows)
    __shared__ __align__(16) short vt[2][4096];   // 64 dh x 64 keys

    const int tid  = threadIdx.x;                 // 0..255
    const int wave = tid >> 6;
    const int lane = tid & 63;
    const int l31 = lane & 31, hi = lane >> 5;
    const int bh = blockIdx.y;
    const int w_ = (blockIdx.x + 4 * bh) & 31;
    const int g2 = ((bh >> 3) & 1) ? (31 - w_) : w_;   // 0..31
    const short* Qp = Qb + (size_t)bh * SEQ * DH;
    const short* Kp = Kb + (size_t)bh * SEQ * DH;
    const short* Vp = Vt + (size_t)bh * DH * SEQ;
    const int bb = bh >> 3, h = bh & 7;
    const int q0 = g2 * 128 + wave * 32;          // this wave's 32 q-rows
    const int myq = q0 + l31;
    const int jdiag = q0 >> 6;                    // wave's diagonal tile
    const int jmax = 2 * g2 + 1;

    // ---- per-thread staging constants (2 chunks per array) ----
    const int ckA = tid, ckB = tid + 256;
    const int RA = ckA >> 3, RB = ckB >> 3;
    const int cA = (ckA & 7) ^ (RA & 7), cB = (ckB & 7) ^ (RB & 7);
    const int RA31 = RA & 31, RB31 = RB & 31;
    const int kkA = (RA & 32) + ((RA31 & 8) << 1) + ((RA31 & 4) << 1)
                  + ((RA31 & 16) >> 2) + (RA31 & 3);
    const int kkB = (RB & 32) + ((RB31 & 8) << 1) + ((RB31 & 4) << 1)
                  + ((RB31 & 16) >> 2) + (RB31 & 3);
    const size_t kOffA = ((size_t)kkA << 6) + cA * 8;
    const size_t kOffB = ((size_t)kkB << 6) + cB * 8;
    const size_t vOffA = (size_t)RA * SEQ + cA * 8;
    const size_t vOffB = (size_t)RB * SEQ + cB * 8;

    bf16x8 sk0, sk1, sv0, sv1;                    // staged regs
    auto load_tile = [&](int j) {
        const size_t k0 = (size_t)j * 64;
        sk0 = *(const bf16x8*)(Kp + (k0 << 6) + kOffA);
        sk1 = *(const bf16x8*)(Kp + (k0 << 6) + kOffB);
        sv0 = *(const bf16x8*)(Vp + vOffA + k0);
        sv1 = *(const bf16x8*)(Vp + vOffB + k0);
    };
    auto write_tile = [&](int buf) {
        *(bf16x8*)&kt[buf][ckA * 8] = sk0;
        *(bf16x8*)&kt[buf][ckB * 8] = sk1;
        *(bf16x8*)&vt[buf][ckA * 8] = sv0;
        *(bf16x8*)&vt[buf][ckB * 8] = sv1;
    };

    // Q B-frags: qf[c] = Q[myq][16c + 8hi .. +7]
    bf16x8 qf[4];
#pragma unroll
    for (int c = 0; c < 4; ++c)
        qf[c] = *(const bf16x8*)(Qp + (size_t)myq * DH + c * 16 + hi * 8);

    // all-ones bf16 A-fragment for the l-reduction MFMA
    const bf16x8 ones = { (short)0x3F80, (short)0x3F80, (short)0x3F80,
                          (short)0x3F80, (short)0x3F80, (short)0x3F80,
                          (short)0x3F80, (short)0x3F80 };

    f32x16 o0 = {}, o1 = {};
    f32x16 lacc = {};                             // every reg = sum_k P[k][q=l31]

    load_tile(0);
    write_tile(0);
    load_tile(1);
    BAR();

    for (int j = 0; j <= jmax; ++j) {
        const int cur = j & 1;
        if (j < jmax) {
            write_tile(cur ^ 1);                  // regs from 1 iter ago
            if (j + 1 < jmax) load_tile(j + 2);   // in flight over 2 iters
        }

        // fully-masked tile for this wave? (wave-uniform -> no divergence)
        if ((j << 6) <= q0 + 31) {
            // ---- S^T = K.Q^T, two 32-key subtiles ----
            f32x16 s0 = {}, s1 = {};
            const int sw = l31 & 7;
            __builtin_amdgcn_s_setprio(1);
#pragma unroll
            for (int c = 0; c < 4; ++c) {
                const int pc = ((2 * c + hi) ^ sw) * 8;
                bf16x8 a0 = *(const bf16x8*)(&kt[cur][l31 * 64 + pc]);
                bf16x8 a1 = *(const bf16x8*)(&kt[cur][(32 + l31) * 64 + pc]);
                s0 = __builtin_amdgcn_mfma_f32_32x32x16_bf16(a0, qf[c], s0, 0, 0, 0);
                s1 = __builtin_amdgcn_mfma_f32_32x32x16_bf16(a1, qf[c], s1, 0, 0, 0);
            }
            __builtin_amdgcn_s_setprio(0);
            // ---- causal mask at/after this wave's diagonal (kappa indices) ----
            if (j >= jdiag) {
                const int k0 = j * 64;
#pragma unroll
                for (int reg = 0; reg < 16; ++reg) {
                    const int kl = ((reg >> 2) & 1) * 16 + hi * 8
                                 + ((reg >> 3) & 1) * 4 + (reg & 3);
                    if (k0 + kl > myq)      s0[reg] = -3e38f;
                    if (k0 + 32 + kl > myq) s1[reg] = -3e38f;
                }
            }
            // ---- NO-MAX softmax: p = exp2(s), raw HW op ----
#pragma unroll
            for (int i = 0; i < 16; ++i) {
                s0[i] = __builtin_amdgcn_exp2f(s0[i]);
                s1[i] = __builtin_amdgcn_exp2f(s1[i]);
            }

            // ---- P B-frags straight from C regs (kappa permutation) ----
            union { uint32_t u[4]; bf16x8 v; } p00, p01, p10, p11;
            p00.u[0] = pkbf(s0[0], s0[1]);   p00.u[1] = pkbf(s0[2], s0[3]);
            p00.u[2] = pkbf(s0[8], s0[9]);   p00.u[3] = pkbf(s0[10], s0[11]);
            p01.u[0] = pkbf(s0[4], s0[5]);   p01.u[1] = pkbf(s0[6], s0[7]);
            p01.u[2] = pkbf(s0[12], s0[13]); p01.u[3] = pkbf(s0[14], s0[15]);
            p10.u[0] = pkbf(s1[0], s1[1]);   p10.u[1] = pkbf(s1[2], s1[3]);
            p10.u[2] = pkbf(s1[8], s1[9]);   p10.u[3] = pkbf(s1[10], s1[11]);
            p11.u[0] = pkbf(s1[4], s1[5]);   p11.u[1] = pkbf(s1[6], s1[7]);
            p11.u[2] = pkbf(s1[12], s1[13]); p11.u[3] = pkbf(s1[14], s1[15]);

            __builtin_amdgcn_s_setprio(1);
            // ---- l on the MFMA pipe: lacc += 1 * P ----
            lacc = __builtin_amdgcn_mfma_f32_32x32x16_bf16(ones, p00.v, lacc, 0, 0, 0);
            lacc = __builtin_amdgcn_mfma_f32_32x32x16_bf16(ones, p01.v, lacc, 0, 0, 0);
            lacc = __builtin_amdgcn_mfma_f32_32x32x16_bf16(ones, p10.v, lacc, 0, 0, 0);
            lacc = __builtin_amdgcn_mfma_f32_32x32x16_bf16(ones, p11.v, lacc, 0, 0, 0);

            // ---- O^T += V^T . P : two 32-dh tiles ----
            {
                const short* vrow = &vt[cur][l31 * 64];
                bf16x8 v00 = *(const bf16x8*)(vrow + (((0 + hi) ^ sw) * 8));
                bf16x8 v01 = *(const bf16x8*)(vrow + (((2 + hi) ^ sw) * 8));
                bf16x8 v10 = *(const bf16x8*)(vrow + (((4 + hi) ^ sw) * 8));
                bf16x8 v11 = *(const bf16x8*)(vrow + (((6 + hi) ^ sw) * 8));
                o0 = __builtin_amdgcn_mfma_f32_32x32x16_bf16(v00, p00.v, o0, 0, 0, 0);
                o0 = __builtin_amdgcn_mfma_f32_32x32x16_bf16(v01, p01.v, o0, 0, 0, 0);
                o0 = __builtin_amdgcn_mfma_f32_32x32x16_bf16(v10, p10.v, o0, 0, 0, 0);
                o0 = __builtin_amdgcn_mfma_f32_32x32x16_bf16(v11, p11.v, o0, 0, 0, 0);
            }
            {
                const short* vrow = &vt[cur][(32 + l31) * 64];
                bf16x8 v00 = *(const bf16x8*)(vrow + (((0 + hi) ^ sw) * 8));
                bf16x8 v01 = *(const bf16x8*)(vrow + (((2 + hi) ^ sw) * 8));
                bf16x8 v10 = *(const bf16x8*)(vrow + (((4 + hi) ^ sw) * 8));
                bf16x8 v11 = *(const bf16x8*)(vrow + (((6 + hi) ^ sw) * 8));
                o1 = __builtin_amdgcn_mfma_f32_32x32x16_bf16(v00, p00.v, o1, 0, 0, 0);
                o1 = __builtin_amdgcn_mfma_f32_32x32x16_bf16(v01, p01.v, o1, 0, 0, 0);
                o1 = __builtin_amdgcn_mfma_f32_32x32x16_bf16(v10, p10.v, o1, 0, 0, 0);
                o1 = __builtin_amdgcn_mfma_f32_32x32x16_bf16(v11, p11.v, o1, 0, 0, 0);
            }
            __builtin_amdgcn_s_setprio(0);
        }
        BAR();
    }
    // ---- normalize by lacc[0] (full sum; identical in both half-waves) ----
    const float inv = 1.0f / lacc[0];
    short* orow = ao + (size_t)(bb * SEQ + myq) * D_MODEL + h * DH;
#pragma unroll
    for (int c = 0; c < 4; ++c) {
        uint2 st;
        st.x = pkbf(o0[4 * c] * inv,     o0[4 * c + 1] * inv);
        st.y = pkbf(o0[4 * c + 2] * inv, o0[4 * c + 3] * inv);
        *(uint2*)(orow + 8 * c + 4 * hi) = st;
    }
#pragma unroll
    for (int c = 0; c < 4; ++c) {
        uint2 st;
        st.x = pkbf(o1[4 * c] * inv,     o1[4 * c + 1] * inv);
        st.y = pkbf(o1[4 * c + 2] * inv, o1[4 * c + 3] * inv);
        *(uint2*)(orow + 32 + 8 * c + 4 * hi) = st;
    }
}

// ---------------------------------------------------------------------------
// Kernel 3: output projection, all-bf16, gload_lds with 3-buffer rotation +
// counted vmcnt (3 loads/stage).  64m x 128n tiles (512 blocks, 2/CU).
// ---------------------------------------------------------------------------
__global__ __launch_bounds__(256) void proj_kernel(
    const short* __restrict__ attn, const short* __restrict__ Wpb,
    const float* __restrict__ bias, float* __restrict__ out)
{
    __shared__ __align__(16) short at[3][2048];   // 3 x (64 x 32)
    __shared__ __align__(16) short bt[3][4096];   // 3 x (128 x 32)

    const int tid  = threadIdx.x;
    const int wave = tid >> 6;
    const int lane = tid & 63;
    const int ln = lane & 15, quad = lane >> 4;
    const int m0 = blockIdx.x * 64;
    const int n0 = blockIdx.y * 128;
    const int mh = (wave & 1) * 32, nh = (wave >> 1) * 64;

    const int RA = tid >> 2, cAc = (tid & 3) ^ SWZ(RA);
    const int ck0 = tid, ck1 = tid + 256;
    const int R0 = ck0 >> 2, R1 = ck1 >> 2;
    const int c0 = (ck0 & 3) ^ SWZ(R0), c1 = (ck1 & 3) ^ SWZ(R1);
    const int lbase = (tid & 192) * 8;            // wave-uniform chunk base

    auto stage = [&](int buf, int kc) {
        const short* gA = attn + (size_t)(m0 + RA) * D_MODEL + kc + cAc * 8;
        const short* gB0 = Wpb + (size_t)(n0 + R0) * D_MODEL + kc + c0 * 8;
        const short* gB1 = Wpb + (size_t)(n0 + R1) * D_MODEL + kc + c1 * 8;
        gload16(gA, &at[buf][lbase]);
        gload16(gB0, &bt[buf][lbase]);
        gload16(gB1, &bt[buf][lbase] + 2048);
    };

    f32x4 acc[2][4] = {};

    stage(0, 0);
    stage(1, 32);

    for (int s = 0; s < 16; ++s) {
        const int cur = s % 3;
        if (s == 15) BARC(0); else BARC(3);
        if (s < 14) stage((s + 2) % 3, (s + 2) * 32);

        bf16x8 a[2], b[4];
#pragma unroll
        for (int i = 0; i < 2; ++i) {
            const int R = mh + i * 16 + ln;
            a[i] = *(const bf16x8*)(&at[cur][R * 32 + ((quad ^ SWZ(R)) * 8)]);
        }
#pragma unroll
        for (int j = 0; j < 4; ++j) {
            const int R = nh + j * 16 + ln;
            b[j] = *(const bf16x8*)(&bt[cur][R * 32 + ((quad ^ SWZ(R)) * 8)]);
        }
        __builtin_amdgcn_s_setprio(1);
#pragma unroll
        for (int i = 0; i < 2; ++i)
#pragma unroll
            for (int j = 0; j < 4; ++j)
                acc[i][j] = __builtin_amdgcn_mfma_f32_16x16x32_bf16(
                    a[i], b[j], acc[i][j], 0, 0, 0);
        __builtin_amdgcn_s_setprio(0);
    }
#pragma unroll
    for (int j = 0; j < 4; ++j) {
        const int n = n0 + nh + j * 16 + ln;
        const float bv = bias[n];
#pragma unroll
        for (int i = 0; i < 2; ++i)
#pragma unroll
            for (int r = 0; r < 4; ++r) {
                const int row = m0 + mh + i * 16 + quad * 4 + r;
                out[(size_t)row * D_MODEL + n] = acc[i][j][r] + bv;
            }
    }
}

extern "C" void kernel_launch(void* const* d_in, const int* in_sizes, int n_in,
                              void* d_out, int out_size, void* d_ws, size_t ws_size,
                              hipStream_t stream) {
    const float* x  = (const float*)d_in[0];
    const float* Wq = (const float*)d_in[1];
    const float* Wk = (const float*)d_in[2];
    const float* Wv = (const float*)d_in[3];
    const float* Wp = (const float*)d_in[4];
    const float* bp = (const float*)d_in[5];
    float* out = (float*)d_out;

    // workspace: Qb | Kb | Vt | ab (4 x 8 MB bf16) | Wb (4 x 0.5 MB bf16)
    short* Qb = (short*)d_ws;
    short* Kb = Qb + (size_t)NBH * SEQ * DH;
    short* Vt = Kb + (size_t)NBH * SEQ * DH;
    short* ab = Vt + (size_t)NBH * SEQ * DH;
    short* Wb = ab + (size_t)NBH * SEQ * DH;

    // xb (8.4 MB bf16) lives in d_out (16.78 MB), dead until proj overwrites
    short* xb = (short*)d_out;

    cvt_pre<<<dim3((NX + 4 * NW) / (8 * 256)), 256, 0, stream>>>(
        x, Wq, Wk, Wv, Wp, xb, Wb);
    qkv_kernel<<<dim3(64, 4, 3), 256, 0, stream>>>(xb, Wb, Qb, Kb, Vt);
    attn_kernel<<<dim3(32, NBH), 256, 0, stream>>>(Qb, Kb, Vt, ab);
    proj_kernel<<<dim3(128, 4), 256, 0, stream>>>(ab, Wb + 3 * (size_t)NW, bp, out);
}